// Round 1
// baseline (293.919 us; speedup 1.0000x reference)
//
#include <hip/hip_runtime.h>
#include <hip/hip_bf16.h>

typedef short s8v __attribute__((ext_vector_type(8)));   // 8 bf16 (4 VGPRs) MFMA A/B frag
typedef float f4v __attribute__((ext_vector_type(4)));   // 4 fp32 MFMA C/D frag

__device__ __forceinline__ unsigned int bfround(float f) {
    unsigned int x = __float_as_uint(f);
    return (x + 0x7fffu + ((x >> 16) & 1u)) >> 16;  // RNE fp32->bf16
}
// packed RNE fp32x2 -> bf16x2 (v_cvt_pk_bf16_f32 on gfx950)
__device__ __forceinline__ unsigned int pkbf(float x, float y) {
    __hip_bfloat162 h = __float22bfloat162_rn(make_float2(x, y));
    return *(unsigned int*)&h;
}
// signed-int8 extract byte k of word w -> float  (v_bfe_i32 + v_cvt_f32_i32)
__device__ __forceinline__ float i8f(unsigned int w, int k) {
    return (float)((int)(signed char)(w >> (8 * k)));
}

// Pack W1 (fp32, [256x128]) into bf16 MFMA B-fragments laid out per-lane so proj
// waves read them with fully-coalesced uint4 loads.
// WF[half][c][t][lane] : uint4 = 8 bf16, j=0..7, k = c*32 + (lane>>4)*8 + j, col = t*16 + (lane&15)
__global__ __launch_bounds__(256) void pack_w(const float* __restrict__ W1,
                                              uint4* __restrict__ WF)
{
    const int half = blockIdx.x;
    #pragma unroll
    for (int iter = 0; iter < 8; ++iter) {
        int idx  = iter * 256 + threadIdx.x;   // (c,t,lane) flattened
        int lane = idx & 63;
        int t    = (idx >> 6) & 7;
        int c    = idx >> 9;
        int q = lane >> 4, m = lane & 15;
        unsigned int w[4];
        #pragma unroll
        for (int jj = 0; jj < 4; ++jj) {
            float lo = W1[(size_t)(half * 128 + c * 32 + q * 8 + 2 * jj    ) * 128 + t * 16 + m];
            float hi = W1[(size_t)(half * 128 + c * 32 + q * 8 + 2 * jj + 1) * 128 + t * 16 + m];
            w[jj] = bfround(lo) | (bfround(hi) << 16);
        }
        WF[(size_t)half * 2048 + idx] = make_uint4(w[0], w[1], w[2], w[3]);
    }
}

// Projection v6: W fragments staged in LDS (32KB/block, shared by 4 waves)
// instead of 128 persistent VGPRs; prefetched A tile is converted to bf16
// frags at end-of-tile so only 16 regs of A stay live through compute.
// Target <=128 unified VGPR/wave -> 4 waves/SIMD (was ~2) to hide L3/HBM
// latency. Blocks [0,bph)=users, [bph,2bph)=movies.
// int8 rows + per-row fp32 scale, column perm(t*16+m) = m*8+t.
__global__ __launch_bounds__(256, 4) void proj_kernel(
    const float* __restrict__ userf, const float* __restrict__ movief,
    const uint4* __restrict__ WF, const float* __restrict__ b1,
    uint2* __restrict__ Pu, uint2* __restrict__ Pm,
    float* __restrict__ SU, float* __restrict__ SM,
    int ntiles, int bph)
{
    __shared__ uint4 wlds[2048];   // 32KB: this half's 32 B-fragments

    const int half = blockIdx.x >= bph;
    const int bid  = half ? blockIdx.x - bph : blockIdx.x;
    const float* __restrict__ feat = half ? movief : userf;
    uint2* __restrict__ P = half ? Pm : Pu;
    float* __restrict__ S = half ? SM : SU;
    const uint4* __restrict__ wfh = WF + (size_t)half * 2048;

    // Cooperative LDS fill: 2048 uint4 / 256 threads = 8 each (128B/thread).
    #pragma unroll
    for (int i = 0; i < 8; ++i)
        wlds[i * 256 + threadIdx.x] = wfh[i * 256 + threadIdx.x];
    __syncthreads();

    const int lane = threadIdx.x & 63;
    const int m    = lane & 15;
    const int q    = lane >> 4;

    float bias_v[8];
    #pragma unroll
    for (int t = 0; t < 8; ++t)
        bias_v[t] = half ? b1[t * 16 + m] : 0.0f;

    const int wid = bid * 4 + (threadIdx.x >> 6);   // wave id within half
    const int nw  = bph * 4;                        // waves per half

#define LOAD_A(dst, t_) do {                                            \
        const float4* arow_ = (const float4*)feat + (size_t)(t_) * 512; \
        _Pragma("unroll")                                               \
        for (int c_ = 0; c_ < 4; ++c_) {                                \
            dst[c_][0] = arow_[m * 32 + c_ * 8 + q * 2 + 0];            \
            dst[c_][1] = arow_[m * 32 + c_ * 8 + q * 2 + 1];            \
        }                                                               \
    } while (0)

// fp32 prefetch regs -> bf16 A-frags (releases an[] for next prefetch)
#define CVT_A() do {                                                    \
        _Pragma("unroll")                                               \
        for (int c_ = 0; c_ < 4; ++c_) {                                \
            uint4 aw_;                                                  \
            aw_.x = pkbf(an[c_][0].x, an[c_][0].y);                     \
            aw_.y = pkbf(an[c_][0].z, an[c_][0].w);                     \
            aw_.z = pkbf(an[c_][1].x, an[c_][1].y);                     \
            aw_.w = pkbf(an[c_][1].z, an[c_][1].w);                     \
            af[c_] = *(const s8v*)&aw_;                                 \
        }                                                               \
    } while (0)

    float4 an[4][2];   // in-flight prefetch (fp32)
    s8v    af[4];      // current tile's A-frags (bf16, 16 regs)
    int tile = wid;
    if (tile < ntiles) {
        LOAD_A(an, tile);
        CVT_A();       // prologue: stall on first load here
    }

    while (tile < ntiles) {
        const int nxt = tile + nw;
        if (nxt < ntiles) LOAD_A(an, nxt);   // in flight across this tile's compute

        f4v acc[8];
        #pragma unroll
        for (int t = 0; t < 8; ++t)
            acc[t] = (f4v){bias_v[t], bias_v[t], bias_v[t], bias_v[t]};

        #pragma unroll
        for (int c = 0; c < 4; ++c) {
            #pragma unroll
            for (int t = 0; t < 8; ++t) {
                uint4 f = wlds[(c * 8 + t) * 64 + lane];   // lane-contiguous, conflict-free
                acc[t] = __builtin_amdgcn_mfma_f32_16x16x32_bf16(af[c], *(const s8v*)&f, acc[t], 0, 0, 0);
            }
        }

        // C/D layout: col = t*16+m, row = q*4+r  [m89/m91 verified]. int8-quantize
        // each row; absmax over the 16-lane m-group (xor 1..8 stays in-group).
        #pragma unroll
        for (int r = 0; r < 4; ++r) {
            float mx = 0.0f;
            #pragma unroll
            for (int t = 0; t < 8; ++t) mx = fmaxf(mx, fabsf(acc[t][r]));
            #pragma unroll
            for (int off = 1; off < 16; off <<= 1)
                mx = fmaxf(mx, __shfl_xor(mx, off, 64));
            float inv = mx > 0.0f ? 127.0f / mx : 0.0f;

            unsigned int lo = 0, hi = 0;
            #pragma unroll
            for (int t = 0; t < 4; ++t) {
                lo |= ((unsigned int)(__float2int_rn(acc[t][r]     * inv) & 0xff)) << (8 * t);
                hi |= ((unsigned int)(__float2int_rn(acc[t + 4][r] * inv) & 0xff)) << (8 * t);
            }
            int row = tile * 16 + q * 4 + r;
            P[(size_t)row * 16 + m] = make_uint2(lo, hi);  // 16 lanes x 8B = one 128B row
            if (m == 0) S[row] = mx * (1.0f / 127.0f);
        }

        if (nxt < ntiles) CVT_A();   // waits on prefetch; overlapped by the MFMAs above
        tile = nxt;
    }
#undef LOAD_A
#undef CVT_A
}

// out[e] = relu(su*Qu[src] + sm*Qm[dst]) . W2 + b2   (b1 folded into Pm; perm'd dims)
// 16 lanes/edge (uint2 = 8 int8 dims per lane), 16 edges/wave.
__global__ __launch_bounds__(256) void edge_kernel(
    const int* __restrict__ src, const int* __restrict__ dst,
    const uint2* __restrict__ Pu, const uint2* __restrict__ Pm,
    const float* __restrict__ SU, const float* __restrict__ SM,
    const float* __restrict__ W2, const float* __restrict__ b2,
    float* __restrict__ out)
{
    const int lane = threadIdx.x & 63;
    const int L    = lane & 15;      // sub-lane within edge group
    const int g    = lane >> 4;      // edge group 0..3
    const int eg   = (blockIdx.x * 4 + (threadIdx.x >> 6)) * 16 + g * 4;

    // W2 at perm position L*8+j is original col j*16+L
    float w2v[8];
    #pragma unroll
    for (int j = 0; j < 8; ++j) w2v[j] = W2[j * 16 + L];

    int si[4], di[4];
    #pragma unroll
    for (int i = 0; i < 4; ++i) { si[i] = src[eg + i]; di[i] = dst[eg + i]; }

    uint2 pu[4], pm[4];
    float scu[4], scm[4];
    #pragma unroll
    for (int i = 0; i < 4; ++i) {
        pu[i] = Pu[(size_t)si[i] * 16 + L];   // 8B/lane, one 128B line per 16-lane group
        pm[i] = Pm[(size_t)di[i] * 16 + L];
        scu[i] = SU[si[i]];                   // 400KB arrays, L2-resident
        scm[i] = SM[di[i]];
    }

    float res[4];
    #pragma unroll
    for (int i = 0; i < 4; ++i) {
        const unsigned int uw[2] = {pu[i].x, pu[i].y};
        const unsigned int mw[2] = {pm[i].x, pm[i].y};
        float acc = 0.0f;
        #pragma unroll
        for (int v = 0; v < 2; ++v) {
            #pragma unroll
            for (int k = 0; k < 4; ++k) {
                float h = fmaf(scu[i], i8f(uw[v], k), scm[i] * i8f(mw[v], k));
                acc = fmaf(fmaxf(h, 0.0f), w2v[v * 4 + k], acc);
            }
        }
        #pragma unroll
        for (int off = 1; off < 16; off <<= 1)
            acc += __shfl_xor(acc, off, 64);
        res[i] = acc;
    }

    if (L == 0) {
        float bb = b2[0];
        *(float4*)(out + eg) = make_float4(res[0] + bb, res[1] + bb, res[2] + bb, res[3] + bb);
    }
}

extern "C" void kernel_launch(void* const* d_in, const int* in_sizes, int n_in,
                              void* d_out, int out_size, void* d_ws, size_t ws_size,
                              hipStream_t stream) {
    const float* userf  = (const float*)d_in[0];
    const float* movief = (const float*)d_in[1];
    const int*   eidx   = (const int*)d_in[2];
    const float* W1     = (const float*)d_in[3];
    const float* b1     = (const float*)d_in[4];
    const float* W2     = (const float*)d_in[5];
    const float* b2     = (const float*)d_in[6];
    float* out = (float*)d_out;

    const int NU = in_sizes[0] / 128;   // 100000
    const int NM = in_sizes[1] / 128;   // 100000
    const int E  = in_sizes[2] / 2;     // 1000000

    // Workspace: Qu 12.8MB | Qm 12.8MB | SU 400KB | SM 400KB | WF 64KB
    uint2* Pu = (uint2*)d_ws;
    uint2* Pm = Pu + (size_t)NU * 16;
    float* SU = (float*)(Pm + (size_t)NM * 16);
    float* SM = SU + NU;
    uint4* WF = (uint4*)(SM + NM);

    const int ntiles = NU / 16;   // 6250 per half
    const int bph    = 512;       // 2048 waves/half, ~3 tiles/wave

    pack_w<<<2, 256, 0, stream>>>(W1, WF);
    proj_kernel<<<2 * bph, 256, 0, stream>>>(userf, movief, WF, b1, Pu, Pm, SU, SM, ntiles, bph);
    edge_kernel<<<E / 64, 256, 0, stream>>>(eidx, eidx + E, Pu, Pm, SU, SM, W2, b2, out);
}

// Round 2
// 276.833 us; speedup vs baseline: 1.0617x; 1.0617x over previous
//
#include <hip/hip_runtime.h>
#include <hip/hip_bf16.h>

typedef short s8v __attribute__((ext_vector_type(8)));   // 8 bf16 (4 VGPRs) MFMA A/B frag
typedef float f4v __attribute__((ext_vector_type(4)));   // 4 fp32 MFMA C/D frag

__device__ __forceinline__ unsigned int bfround(float f) {
    unsigned int x = __float_as_uint(f);
    return (x + 0x7fffu + ((x >> 16) & 1u)) >> 16;  // RNE fp32->bf16
}
// packed RNE fp32x2 -> bf16x2 (v_cvt_pk_bf16_f32 on gfx950)
__device__ __forceinline__ unsigned int pkbf(float x, float y) {
    __hip_bfloat162 h = __float22bfloat162_rn(make_float2(x, y));
    return *(unsigned int*)&h;
}
// signed-int8 extract byte k of word w -> float  (v_bfe_i32 + v_cvt_f32_i32)
__device__ __forceinline__ float i8f(unsigned int w, int k) {
    return (float)((int)(signed char)(w >> (8 * k)));
}

// Pack W1 (fp32, [256x128]) into bf16 MFMA B-fragments laid out per-lane so proj
// waves read them with fully-coalesced uint4 loads.
// WF[half][c][t][lane] : uint4 = 8 bf16, j=0..7, k = c*32 + (lane>>4)*8 + j, col = t*16 + (lane&15)
__global__ __launch_bounds__(256) void pack_w(const float* __restrict__ W1,
                                              uint4* __restrict__ WF)
{
    const int half = blockIdx.x;
    #pragma unroll
    for (int iter = 0; iter < 8; ++iter) {
        int idx  = iter * 256 + threadIdx.x;   // (c,t,lane) flattened
        int lane = idx & 63;
        int t    = (idx >> 6) & 7;
        int c    = idx >> 9;
        int q = lane >> 4, m = lane & 15;
        unsigned int w[4];
        #pragma unroll
        for (int jj = 0; jj < 4; ++jj) {
            float lo = W1[(size_t)(half * 128 + c * 32 + q * 8 + 2 * jj    ) * 128 + t * 16 + m];
            float hi = W1[(size_t)(half * 128 + c * 32 + q * 8 + 2 * jj + 1) * 128 + t * 16 + m];
            w[jj] = bfround(lo) | (bfround(hi) << 16);
        }
        WF[(size_t)half * 2048 + idx] = make_uint4(w[0], w[1], w[2], w[3]);
    }
}

// Projection v7: W fragments staged in LDS (32KB/block, shared by 4 waves);
// A prefetched one tile ahead in fp32 regs, converted to bf16 at end-of-tile.
// v6's __launch_bounds__(256,4) capped the unified file at 128 regs/wave ->
// allocator spilled the prefetch buffer to scratch (+390MB HBM traffic/iter,
// 155us). Steady-state demand is ~112 regs (an 32 + af 16 + acc 32 + bias 8
// + addr/temps), so cap at 3 waves/SIMD (~170 regs): zero spill, 12 waves/CU.
// Blocks [0,bph)=users, [bph,2bph)=movies.
// int8 rows + per-row fp32 scale, column perm(t*16+m) = m*8+t.
__global__ __launch_bounds__(256, 3) void proj_kernel(
    const float* __restrict__ userf, const float* __restrict__ movief,
    const uint4* __restrict__ WF, const float* __restrict__ b1,
    uint2* __restrict__ Pu, uint2* __restrict__ Pm,
    float* __restrict__ SU, float* __restrict__ SM,
    int ntiles, int bph)
{
    __shared__ uint4 wlds[2048];   // 32KB: this half's 32 B-fragments

    const int half = blockIdx.x >= bph;
    const int bid  = half ? blockIdx.x - bph : blockIdx.x;
    const float* __restrict__ feat = half ? movief : userf;
    uint2* __restrict__ P = half ? Pm : Pu;
    float* __restrict__ S = half ? SM : SU;
    const uint4* __restrict__ wfh = WF + (size_t)half * 2048;

    // Cooperative LDS fill: 2048 uint4 / 256 threads = 8 each (128B/thread).
    #pragma unroll
    for (int i = 0; i < 8; ++i)
        wlds[i * 256 + threadIdx.x] = wfh[i * 256 + threadIdx.x];
    __syncthreads();

    const int lane = threadIdx.x & 63;
    const int m    = lane & 15;
    const int q    = lane >> 4;

    float bias_v[8];
    #pragma unroll
    for (int t = 0; t < 8; ++t)
        bias_v[t] = half ? b1[t * 16 + m] : 0.0f;

    const int wid = bid * 4 + (threadIdx.x >> 6);   // wave id within half
    const int nw  = bph * 4;                        // waves per half

#define LOAD_A(dst, t_) do {                                            \
        const float4* arow_ = (const float4*)feat + (size_t)(t_) * 512; \
        _Pragma("unroll")                                               \
        for (int c_ = 0; c_ < 4; ++c_) {                                \
            dst[c_][0] = arow_[m * 32 + c_ * 8 + q * 2 + 0];            \
            dst[c_][1] = arow_[m * 32 + c_ * 8 + q * 2 + 1];            \
        }                                                               \
    } while (0)

// fp32 prefetch regs -> bf16 A-frags (releases an[] for next prefetch)
#define CVT_A() do {                                                    \
        _Pragma("unroll")                                               \
        for (int c_ = 0; c_ < 4; ++c_) {                                \
            uint4 aw_;                                                  \
            aw_.x = pkbf(an[c_][0].x, an[c_][0].y);                     \
            aw_.y = pkbf(an[c_][0].z, an[c_][0].w);                     \
            aw_.z = pkbf(an[c_][1].x, an[c_][1].y);                     \
            aw_.w = pkbf(an[c_][1].z, an[c_][1].w);                     \
            af[c_] = *(const s8v*)&aw_;                                 \
        }                                                               \
    } while (0)

    float4 an[4][2];   // in-flight prefetch (fp32)
    s8v    af[4];      // current tile's A-frags (bf16, 16 regs)
    int tile = wid;
    if (tile < ntiles) {
        LOAD_A(an, tile);
        CVT_A();       // prologue: stall on first load here
    }

    while (tile < ntiles) {
        const int nxt = tile + nw;
        if (nxt < ntiles) LOAD_A(an, nxt);   // in flight across this tile's compute

        f4v acc[8];
        #pragma unroll
        for (int t = 0; t < 8; ++t)
            acc[t] = (f4v){bias_v[t], bias_v[t], bias_v[t], bias_v[t]};

        #pragma unroll
        for (int c = 0; c < 4; ++c) {
            #pragma unroll
            for (int t = 0; t < 8; ++t) {
                uint4 f = wlds[(c * 8 + t) * 64 + lane];   // lane-contiguous, conflict-free
                acc[t] = __builtin_amdgcn_mfma_f32_16x16x32_bf16(af[c], *(const s8v*)&f, acc[t], 0, 0, 0);
            }
        }

        // C/D layout: col = t*16+m, row = q*4+r  [m89/m91 verified]. int8-quantize
        // each row; absmax over the 16-lane m-group (xor 1..8 stays in-group).
        #pragma unroll
        for (int r = 0; r < 4; ++r) {
            float mx = 0.0f;
            #pragma unroll
            for (int t = 0; t < 8; ++t) mx = fmaxf(mx, fabsf(acc[t][r]));
            #pragma unroll
            for (int off = 1; off < 16; off <<= 1)
                mx = fmaxf(mx, __shfl_xor(mx, off, 64));
            float inv = mx > 0.0f ? 127.0f / mx : 0.0f;

            unsigned int lo = 0, hi = 0;
            #pragma unroll
            for (int t = 0; t < 4; ++t) {
                lo |= ((unsigned int)(__float2int_rn(acc[t][r]     * inv) & 0xff)) << (8 * t);
                hi |= ((unsigned int)(__float2int_rn(acc[t + 4][r] * inv) & 0xff)) << (8 * t);
            }
            int row = tile * 16 + q * 4 + r;
            P[(size_t)row * 16 + m] = make_uint2(lo, hi);  // 16 lanes x 8B = one 128B row
            if (m == 0) S[row] = mx * (1.0f / 127.0f);
        }

        if (nxt < ntiles) CVT_A();   // waits on prefetch; overlapped by the MFMAs above
        tile = nxt;
    }
#undef LOAD_A
#undef CVT_A
}

// out[e] = relu(su*Qu[src] + sm*Qm[dst]) . W2 + b2   (b1 folded into Pm; perm'd dims)
// 16 lanes/edge (uint2 = 8 int8 dims per lane), 16 edges/wave.
__global__ __launch_bounds__(256) void edge_kernel(
    const int* __restrict__ src, const int* __restrict__ dst,
    const uint2* __restrict__ Pu, const uint2* __restrict__ Pm,
    const float* __restrict__ SU, const float* __restrict__ SM,
    const float* __restrict__ W2, const float* __restrict__ b2,
    float* __restrict__ out)
{
    const int lane = threadIdx.x & 63;
    const int L    = lane & 15;      // sub-lane within edge group
    const int g    = lane >> 4;      // edge group 0..3
    const int eg   = (blockIdx.x * 4 + (threadIdx.x >> 6)) * 16 + g * 4;

    // W2 at perm position L*8+j is original col j*16+L
    float w2v[8];
    #pragma unroll
    for (int j = 0; j < 8; ++j) w2v[j] = W2[j * 16 + L];

    int si[4], di[4];
    #pragma unroll
    for (int i = 0; i < 4; ++i) { si[i] = src[eg + i]; di[i] = dst[eg + i]; }

    uint2 pu[4], pm[4];
    float scu[4], scm[4];
    #pragma unroll
    for (int i = 0; i < 4; ++i) {
        pu[i] = Pu[(size_t)si[i] * 16 + L];   // 8B/lane, one 128B line per 16-lane group
        pm[i] = Pm[(size_t)di[i] * 16 + L];
        scu[i] = SU[si[i]];                   // 400KB arrays, L2-resident
        scm[i] = SM[di[i]];
    }

    float res[4];
    #pragma unroll
    for (int i = 0; i < 4; ++i) {
        const unsigned int uw[2] = {pu[i].x, pu[i].y};
        const unsigned int mw[2] = {pm[i].x, pm[i].y};
        float acc = 0.0f;
        #pragma unroll
        for (int v = 0; v < 2; ++v) {
            #pragma unroll
            for (int k = 0; k < 4; ++k) {
                float h = fmaf(scu[i], i8f(uw[v], k), scm[i] * i8f(mw[v], k));
                acc = fmaf(fmaxf(h, 0.0f), w2v[v * 4 + k], acc);
            }
        }
        #pragma unroll
        for (int off = 1; off < 16; off <<= 1)
            acc += __shfl_xor(acc, off, 64);
        res[i] = acc;
    }

    if (L == 0) {
        float bb = b2[0];
        *(float4*)(out + eg) = make_float4(res[0] + bb, res[1] + bb, res[2] + bb, res[3] + bb);
    }
}

extern "C" void kernel_launch(void* const* d_in, const int* in_sizes, int n_in,
                              void* d_out, int out_size, void* d_ws, size_t ws_size,
                              hipStream_t stream) {
    const float* userf  = (const float*)d_in[0];
    const float* movief = (const float*)d_in[1];
    const int*   eidx   = (const int*)d_in[2];
    const float* W1     = (const float*)d_in[3];
    const float* b1     = (const float*)d_in[4];
    const float* W2     = (const float*)d_in[5];
    const float* b2     = (const float*)d_in[6];
    float* out = (float*)d_out;

    const int NU = in_sizes[0] / 128;   // 100000
    const int NM = in_sizes[1] / 128;   // 100000
    const int E  = in_sizes[2] / 2;     // 1000000

    // Workspace: Qu 12.8MB | Qm 12.8MB | SU 400KB | SM 400KB | WF 64KB
    uint2* Pu = (uint2*)d_ws;
    uint2* Pm = Pu + (size_t)NU * 16;
    float* SU = (float*)(Pm + (size_t)NM * 16);
    float* SM = SU + NU;
    uint4* WF = (uint4*)(SM + NM);

    const int ntiles = NU / 16;   // 6250 per half
    const int bph    = 512;       // 2048 waves/half, ~3 tiles/wave

    pack_w<<<2, 256, 0, stream>>>(W1, WF);
    proj_kernel<<<2 * bph, 256, 0, stream>>>(userf, movief, WF, b1, Pu, Pm, SU, SM, ntiles, bph);
    edge_kernel<<<E / 64, 256, 0, stream>>>(eidx, eidx + E, Pu, Pm, SU, SM, W2, b2, out);
}

// Round 3
// 184.350 us; speedup vs baseline: 1.5944x; 1.5017x over previous
//
#include <hip/hip_runtime.h>
#include <hip/hip_bf16.h>

typedef short s8v __attribute__((ext_vector_type(8)));   // 8 bf16 (4 VGPRs) MFMA A/B frag
typedef float f4v __attribute__((ext_vector_type(4)));   // 4 fp32 MFMA C/D frag

__device__ __forceinline__ unsigned int bfround(float f) {
    unsigned int x = __float_as_uint(f);
    return (x + 0x7fffu + ((x >> 16) & 1u)) >> 16;  // RNE fp32->bf16
}
// packed RNE fp32x2 -> bf16x2 (v_cvt_pk_bf16_f32 on gfx950)
__device__ __forceinline__ unsigned int pkbf(float x, float y) {
    __hip_bfloat162 h = __float22bfloat162_rn(make_float2(x, y));
    return *(unsigned int*)&h;
}
// signed-int8 extract byte k of word w -> float  (v_bfe_i32 + v_cvt_f32_i32)
__device__ __forceinline__ float i8f(unsigned int w, int k) {
    return (float)((int)(signed char)(w >> (8 * k)));
}

// Pack W1 (fp32, [256x128]) into bf16 MFMA B-fragments laid out per-lane so proj
// waves read them with fully-coalesced uint4 loads.
// WF[half][c][t][lane] : uint4 = 8 bf16, j=0..7, k = c*32 + (lane>>4)*8 + j, col = t*16 + (lane&15)
__global__ __launch_bounds__(256) void pack_w(const float* __restrict__ W1,
                                              uint4* __restrict__ WF)
{
    const int half = blockIdx.x;
    #pragma unroll
    for (int iter = 0; iter < 8; ++iter) {
        int idx  = iter * 256 + threadIdx.x;   // (c,t,lane) flattened
        int lane = idx & 63;
        int t    = (idx >> 6) & 7;
        int c    = idx >> 9;
        int q = lane >> 4, m = lane & 15;
        unsigned int w[4];
        #pragma unroll
        for (int jj = 0; jj < 4; ++jj) {
            float lo = W1[(size_t)(half * 128 + c * 32 + q * 8 + 2 * jj    ) * 128 + t * 16 + m];
            float hi = W1[(size_t)(half * 128 + c * 32 + q * 8 + 2 * jj + 1) * 128 + t * 16 + m];
            w[jj] = bfround(lo) | (bfround(hi) << 16);
        }
        WF[(size_t)half * 2048 + idx] = make_uint4(w[0], w[1], w[2], w[3]);
    }
}

// Projection v8: A-tile staged via global_load_lds (zero in-flight VGPRs), W in
// LDS. v6/v7 evidence: arch-VGPR budget = 256/waves (even split with acc half),
// so fp32 reg-prefetch (an[4][2]=32 regs) can never fit >2 waves/SIMD without
// spilling. Moving A in-flight data to LDS cuts arch demand to ~58 regs ->
// __launch_bounds__(512,4): 4 waves/SIMD, 16 waves/CU, 2 blocks/CU (64KB LDS).
// Per wave-tile: stage c01 (4x1KB DMA, prefetched during prev quantize) ->
// vmcnt0 -> ds_read pulls -> lgkm0 -> stage c23 into same 4KB -> MFMA c01
// (covers c23 latency) -> vmcnt0 -> pulls -> stage next tile's c01 -> MFMA c23
// -> quantize. Blocks [0,bph)=users, [bph,2bph)=movies.
// int8 rows + per-row fp32 scale, column perm(t*16+m) = m*8+t.
__global__ __launch_bounds__(512, 4) void proj_kernel(
    const float* __restrict__ userf, const float* __restrict__ movief,
    const uint4* __restrict__ WF, const float* __restrict__ b1,
    uint2* __restrict__ Pu, uint2* __restrict__ Pm,
    float* __restrict__ SU, float* __restrict__ SM,
    int ntiles, int bph)
{
    __shared__ uint4 wlds[2048];       // 32KB: this half's 32 W-fragments
    __shared__ uint4 alds[8][4][64];   // 32KB: 4KB/wave A staging (wave-private)

    const int half = blockIdx.x >= bph;
    const int bid  = half ? blockIdx.x - bph : blockIdx.x;
    const float* __restrict__ feat = half ? movief : userf;
    uint2* __restrict__ P = half ? Pm : Pu;
    float* __restrict__ S = half ? SM : SU;
    const uint4* __restrict__ wfh = WF + (size_t)half * 2048;

    // Cooperative W fill: 2048 uint4 / 512 threads = 4 each.
    #pragma unroll
    for (int i = 0; i < 4; ++i)
        wlds[i * 512 + threadIdx.x] = wfh[i * 512 + threadIdx.x];

    const int lane = threadIdx.x & 63;
    const int wv   = threadIdx.x >> 6;
    const int m    = lane & 15;
    const int q    = lane >> 4;

    const int wid = bid * 8 + wv;   // wave id within half
    const int nw  = bph * 8;        // waves per half

    float bias_v[8];
    #pragma unroll
    for (int t = 0; t < 8; ++t)
        bias_v[t] = half ? b1[t * 16 + m] : 0.0f;

    // Per-lane byte offset within a tile: float4 index m*32 + q*2 (c,h folded
    // into immediate). Tile t_ starts at byte t_*8192 (16 rows x 512B).
    const char* gfeat = (const char*)feat;
    const size_t lanebyte = ((size_t)m * 32 + (size_t)q * 2) * 16;

    // DMA one c-pair (4KB): inst (cl,h) -> slot cl*2+h, lane l writes slot[l].
    // Source float4 = tile*512 + m*32 + (cpair*2+cl)*8 + q*2 + h  (== v7 LOAD_A).
#define ISSUE_STAGE(cpair, t_) do {                                            \
        const char* gb_ = gfeat + (size_t)(t_) * 8192 + lanebyte;              \
        _Pragma("unroll")                                                      \
        for (int cl_ = 0; cl_ < 2; ++cl_) {                                    \
            _Pragma("unroll")                                                  \
            for (int h_ = 0; h_ < 2; ++h_) {                                   \
                __builtin_amdgcn_global_load_lds(                              \
                    (const __attribute__((address_space(1))) void*)            \
                        (gb_ + ((cpair) * 2 + cl_) * 128 + h_ * 16),           \
                    (__attribute__((address_space(3))) void*)&alds[wv][cl_ * 2 + h_][0], \
                    16, 0, 0);                                                 \
            }                                                                  \
        }                                                                      \
    } while (0)

// two staged float4 (h0,h1) -> one bf16x8 A-frag (v7 CVT_A order)
#define CVT2(p0, p1, dst) do {                                                 \
        uint4 aw_;                                                             \
        const float4 f0_ = *(const float4*)&(p0);                              \
        const float4 f1_ = *(const float4*)&(p1);                              \
        aw_.x = pkbf(f0_.x, f0_.y); aw_.y = pkbf(f0_.z, f0_.w);                \
        aw_.z = pkbf(f1_.x, f1_.y); aw_.w = pkbf(f1_.z, f1_.w);                \
        dst = *(const s8v*)&aw_;                                               \
    } while (0)

#define MFMA_C(c_, afv) do {                                                   \
        _Pragma("unroll")                                                      \
        for (int t_ = 0; t_ < 8; ++t_) {                                       \
            uint4 wf_ = wlds[((c_) * 8 + t_) * 64 + lane];                     \
            acc[t_] = __builtin_amdgcn_mfma_f32_16x16x32_bf16(                 \
                afv, *(const s8v*)&wf_, acc[t_], 0, 0, 0);                     \
        }                                                                      \
    } while (0)

#define WAIT_VM0()   do { asm volatile("s_waitcnt vmcnt(0)" ::: "memory");  \
                          __builtin_amdgcn_sched_barrier(0); } while (0)
#define WAIT_LGKM0() do { asm volatile("s_waitcnt lgkmcnt(0)" ::: "memory"); \
                          __builtin_amdgcn_sched_barrier(0); } while (0)

    int tile = wid;
    if (tile < ntiles) ISSUE_STAGE(0, tile);   // prefetch c01; barrier drain below completes it

    __syncthreads();   // W visible to all waves

    while (tile < ntiles) {
        const int nxt = tile + nw;

        f4v acc[8];
        #pragma unroll
        for (int t = 0; t < 8; ++t)
            acc[t] = (f4v){bias_v[t], bias_v[t], bias_v[t], bias_v[t]};

        WAIT_VM0();                                 // c01 DMA complete
        uint4 p0 = alds[wv][0][lane], p1 = alds[wv][1][lane];
        uint4 p2 = alds[wv][2][lane], p3 = alds[wv][3][lane];
        s8v af0, af1;
        CVT2(p0, p1, af0);
        CVT2(p2, p3, af1);
        WAIT_LGKM0();                               // pulls done -> region reusable
        ISSUE_STAGE(1, tile);                       // c23 in flight under MFMA c01
        MFMA_C(0, af0);
        MFMA_C(1, af1);

        WAIT_VM0();                                 // c23 DMA complete
        uint4 p4 = alds[wv][0][lane], p5 = alds[wv][1][lane];
        uint4 p6 = alds[wv][2][lane], p7 = alds[wv][3][lane];
        s8v af2, af3;
        CVT2(p4, p5, af2);
        CVT2(p6, p7, af3);
        WAIT_LGKM0();
        if (nxt < ntiles) ISSUE_STAGE(0, nxt);      // next tile's c01 under MFMA c23 + quantize
        MFMA_C(2, af2);
        MFMA_C(3, af3);

        // C/D layout: col = t*16+m, row = q*4+r  [m89/m91 verified]. int8-quantize
        // each row; absmax over the 16-lane m-group (xor 1..8 stays in-group).
        #pragma unroll
        for (int r = 0; r < 4; ++r) {
            float mx = 0.0f;
            #pragma unroll
            for (int t = 0; t < 8; ++t) mx = fmaxf(mx, fabsf(acc[t][r]));
            #pragma unroll
            for (int off = 1; off < 16; off <<= 1)
                mx = fmaxf(mx, __shfl_xor(mx, off, 64));
            float inv = mx > 0.0f ? 127.0f / mx : 0.0f;

            unsigned int lo = 0, hi = 0;
            #pragma unroll
            for (int t = 0; t < 4; ++t) {
                lo |= ((unsigned int)(__float2int_rn(acc[t][r]     * inv) & 0xff)) << (8 * t);
                hi |= ((unsigned int)(__float2int_rn(acc[t + 4][r] * inv) & 0xff)) << (8 * t);
            }
            int row = tile * 16 + q * 4 + r;
            P[(size_t)row * 16 + m] = make_uint2(lo, hi);  // 16 lanes x 8B = one 128B row
            if (m == 0) S[row] = mx * (1.0f / 127.0f);
        }

        tile = nxt;
    }
#undef ISSUE_STAGE
#undef CVT2
#undef MFMA_C
#undef WAIT_VM0
#undef WAIT_LGKM0
}

// out[e] = relu(su*Qu[src] + sm*Qm[dst]) . W2 + b2   (b1 folded into Pm; perm'd dims)
// 16 lanes/edge (uint2 = 8 int8 dims per lane), 16 edges/wave.
__global__ __launch_bounds__(256) void edge_kernel(
    const int* __restrict__ src, const int* __restrict__ dst,
    const uint2* __restrict__ Pu, const uint2* __restrict__ Pm,
    const float* __restrict__ SU, const float* __restrict__ SM,
    const float* __restrict__ W2, const float* __restrict__ b2,
    float* __restrict__ out)
{
    const int lane = threadIdx.x & 63;
    const int L    = lane & 15;      // sub-lane within edge group
    const int g    = lane >> 4;      // edge group 0..3
    const int eg   = (blockIdx.x * 4 + (threadIdx.x >> 6)) * 16 + g * 4;

    // W2 at perm position L*8+j is original col j*16+L
    float w2v[8];
    #pragma unroll
    for (int j = 0; j < 8; ++j) w2v[j] = W2[j * 16 + L];

    int si[4], di[4];
    #pragma unroll
    for (int i = 0; i < 4; ++i) { si[i] = src[eg + i]; di[i] = dst[eg + i]; }

    uint2 pu[4], pm[4];
    float scu[4], scm[4];
    #pragma unroll
    for (int i = 0; i < 4; ++i) {
        pu[i] = Pu[(size_t)si[i] * 16 + L];   // 8B/lane, one 128B line per 16-lane group
        pm[i] = Pm[(size_t)di[i] * 16 + L];
        scu[i] = SU[si[i]];                   // 400KB arrays, L2-resident
        scm[i] = SM[di[i]];
    }

    float res[4];
    #pragma unroll
    for (int i = 0; i < 4; ++i) {
        const unsigned int uw[2] = {pu[i].x, pu[i].y};
        const unsigned int mw[2] = {pm[i].x, pm[i].y};
        float acc = 0.0f;
        #pragma unroll
        for (int v = 0; v < 2; ++v) {
            #pragma unroll
            for (int k = 0; k < 4; ++k) {
                float h = fmaf(scu[i], i8f(uw[v], k), scm[i] * i8f(mw[v], k));
                acc = fmaf(fmaxf(h, 0.0f), w2v[v * 4 + k], acc);
            }
        }
        #pragma unroll
        for (int off = 1; off < 16; off <<= 1)
            acc += __shfl_xor(acc, off, 64);
        res[i] = acc;
    }

    if (L == 0) {
        float bb = b2[0];
        *(float4*)(out + eg) = make_float4(res[0] + bb, res[1] + bb, res[2] + bb, res[3] + bb);
    }
}

extern "C" void kernel_launch(void* const* d_in, const int* in_sizes, int n_in,
                              void* d_out, int out_size, void* d_ws, size_t ws_size,
                              hipStream_t stream) {
    const float* userf  = (const float*)d_in[0];
    const float* movief = (const float*)d_in[1];
    const int*   eidx   = (const int*)d_in[2];
    const float* W1     = (const float*)d_in[3];
    const float* b1     = (const float*)d_in[4];
    const float* W2     = (const float*)d_in[5];
    const float* b2     = (const float*)d_in[6];
    float* out = (float*)d_out;

    const int NU = in_sizes[0] / 128;   // 100000
    const int NM = in_sizes[1] / 128;   // 100000
    const int E  = in_sizes[2] / 2;     // 1000000

    // Workspace: Qu 12.8MB | Qm 12.8MB | SU 400KB | SM 400KB | WF 64KB
    uint2* Pu = (uint2*)d_ws;
    uint2* Pm = Pu + (size_t)NU * 16;
    float* SU = (float*)(Pm + (size_t)NM * 16);
    float* SM = SU + NU;
    uint4* WF = (uint4*)(SM + NM);

    const int ntiles = NU / 16;   // 6250 per half
    const int bph    = 256;       // 2048 waves/half (8 waves/block), all blocks resident

    pack_w<<<2, 256, 0, stream>>>(W1, WF);
    proj_kernel<<<2 * bph, 512, 0, stream>>>(userf, movief, WF, b1, Pu, Pm, SU, SM, ntiles, bph);
    edge_kernel<<<E / 64, 256, 0, stream>>>(eidx, eidx + E, Pu, Pm, SU, SM, W2, b2, out);
}